// Round 2
// baseline (228.947 us; speedup 1.0000x reference)
//
#include <hip/hip_runtime.h>

#define D 128
#define N_GRAPHS 64

typedef unsigned int uint32;
typedef __attribute__((ext_vector_type(8))) _Float16 f16x8;
typedef __attribute__((ext_vector_type(4))) float f32x4;

// fp16 helpers: dword holds 2 fp16 (low = elem 2i, high = elem 2i+1); RNE cvt
__device__ __forceinline__ float hl(uint32 u) {
    return (float)__builtin_bit_cast(_Float16, (unsigned short)(u & 0xFFFF));
}
__device__ __forceinline__ float hh(uint32 u) {
    return (float)__builtin_bit_cast(_Float16, (unsigned short)(u >> 16));
}
__device__ __forceinline__ uint32 h2pair(float a, float b) {
    unsigned short ua = __builtin_bit_cast(unsigned short, (_Float16)a);
    unsigned short ub = __builtin_bit_cast(unsigned short, (_Float16)b);
    return (uint32)ua | ((uint32)ub << 16);
}

// ---------------- prep: zero cnt + pre-convert W1 -> fp16 W^T ----------------
// Replaces the hipMemsetAsync dispatch. Wh[n][kd] holds fp16 pair
// (W1[2kd][n], W1[2kd+1][n]) — the MFMA B-fragment layout, unpadded.
__global__ __launch_bounds__(256) void prep_kernel(int* __restrict__ cnt,
                                                   const float* __restrict__ W1,
                                                   uint32* __restrict__ Wh, int n) {
    int i = blockIdx.x * 256 + threadIdx.x;
    if (i < n) {
        cnt[i] = 0;
    } else if (i < n + D * (D / 2)) {
        int j = i - n;
        int nn = j & 127, kd = j >> 7;  // consecutive threads -> consecutive nn (coalesced reads)
        float v0 = W1[(size_t)(2 * kd) * D + nn];
        float v1 = W1[(size_t)(2 * kd + 1) * D + nn];
        Wh[nn * 64 + kd] = h2pair(v0, v1);
    }
}

// ---------------- fused count_rank + MFMA GEMM (independent, one dispatch) ----
// R1 lesson: gemm hid fully under fill (MfmaUtil 0.9%), but fill's 41MB of
// memory-side atomic RMW made it the 45us top kernel. The c-atomics now live
// in agg (fire-and-forget there); fill is a pure scatter (~5us). So gemm's
// overlap target moves to count_rank — the remaining ~40us atomic stretch,
// dependent only on prep's cnt-zero while gemm depends only on x/Wh.
// Blocks [0, gemmBlocks): hb = fp16(x) @ fp16(W1). Rest: rank/cnt build.
// NOTE: rank/cnt must not alias hb (written concurrently by gemm role).

#define GBM 64

__global__ __launch_bounds__(256) void count_gemm_kernel(
    const float* __restrict__ A, const uint32* __restrict__ Wh,
    uint32* __restrict__ hb, int M, int gemmBlocks,
    const int* __restrict__ dst, int* __restrict__ cnt,
    int* __restrict__ rank, int E) {
    __shared__ uint32 lds[64 * 68];  // As 17408B; reused as C staging in epilogue

    if (blockIdx.x >= gemmBlocks) {
        // ---- count role: in-degree + per-edge rank among its dst's edges ----
        int e = (blockIdx.x - gemmBlocks) * 256 + threadIdx.x;
        if (e < E) rank[e] = atomicAdd(&cnt[dst[e]], 1);
        return;
    }

    // ---- gemm role ----
    uint32* As = lds;  // [64 rows][68 dw]
    int tid = threadIdx.x;
    int row0 = blockIdx.x * GBM;

    // stage A tile: 64x128 fp32 -> fp16 (2048 float4, 8/thread, coalesced)
#pragma unroll
    for (int j = 0; j < 8; ++j) {
        int idx = tid + j * 256;
        int r = idx >> 5, c4 = idx & 31;
        float4 v = make_float4(0.f, 0.f, 0.f, 0.f);
        if (row0 + r < M) v = *(const float4*)&A[(size_t)(row0 + r) * D + c4 * 4];
        As[r * 68 + c4 * 2 + 0] = h2pair(v.x, v.y);
        As[r * 68 + c4 * 2 + 1] = h2pair(v.z, v.w);
    }
    __syncthreads();

    int wave = tid >> 6, lane = tid & 63;
    int quad = lane >> 4, l16 = lane & 15;
    int wr = (wave & 1) * 32;   // wave row base (2 m-tiles)
    int wc = (wave >> 1) * 64;  // wave col base (4 n-tiles)
    f32x4 acc[2][4];
#pragma unroll
    for (int mi = 0; mi < 2; ++mi)
#pragma unroll
        for (int ni = 0; ni < 4; ++ni) acc[mi][ni] = (f32x4){0.f, 0.f, 0.f, 0.f};

#pragma unroll
    for (int ks = 0; ks < 4; ++ks) {
        int kd = ks * 16 + quad * 4;  // dword offset of k0 + quad*8 fp16
        f16x8 a0 = *(f16x8*)&As[(wr + l16) * 68 + kd];
        f16x8 a1 = *(f16x8*)&As[(wr + 16 + l16) * 68 + kd];
        f16x8 b0 = *(const f16x8*)&Wh[(wc + l16) * 64 + kd];
        f16x8 b1 = *(const f16x8*)&Wh[(wc + 16 + l16) * 64 + kd];
        f16x8 b2 = *(const f16x8*)&Wh[(wc + 32 + l16) * 64 + kd];
        f16x8 b3 = *(const f16x8*)&Wh[(wc + 48 + l16) * 64 + kd];
        acc[0][0] = __builtin_amdgcn_mfma_f32_16x16x32_f16(a0, b0, acc[0][0], 0, 0, 0);
        acc[0][1] = __builtin_amdgcn_mfma_f32_16x16x32_f16(a0, b1, acc[0][1], 0, 0, 0);
        acc[0][2] = __builtin_amdgcn_mfma_f32_16x16x32_f16(a0, b2, acc[0][2], 0, 0, 0);
        acc[0][3] = __builtin_amdgcn_mfma_f32_16x16x32_f16(a0, b3, acc[0][3], 0, 0, 0);
        acc[1][0] = __builtin_amdgcn_mfma_f32_16x16x32_f16(a1, b0, acc[1][0], 0, 0, 0);
        acc[1][1] = __builtin_amdgcn_mfma_f32_16x16x32_f16(a1, b1, acc[1][1], 0, 0, 0);
        acc[1][2] = __builtin_amdgcn_mfma_f32_16x16x32_f16(a1, b2, acc[1][2], 0, 0, 0);
        acc[1][3] = __builtin_amdgcn_mfma_f32_16x16x32_f16(a1, b3, acc[1][3], 0, 0, 0);
    }
    __syncthreads();  // done reading As; reuse As region as C staging [64][128] fp16

    unsigned short* cs = (unsigned short*)lds;
#pragma unroll
    for (int mi = 0; mi < 2; ++mi)
#pragma unroll
        for (int ni = 0; ni < 4; ++ni)
#pragma unroll
            for (int r = 0; r < 4; ++r) {
                int row = wr + mi * 16 + quad * 4 + r;
                int col2 = wc + ni * 16 + l16;
                cs[row * 128 + col2] =
                    __builtin_bit_cast(unsigned short, (_Float16)acc[mi][ni][r]);
            }
    __syncthreads();
    // coalesced write-out: 64 rows x 16 uint4; C-staging row = 128 fp16 = 64 dwords
#pragma unroll
    for (int j = 0; j < 4; ++j) {
        int idx = tid + j * 256;
        int r = idx >> 4, q = idx & 15;
        if (row0 + r < M)
            *(uint4*)&hb[(size_t)(row0 + r) * 64 + q * 4] = *(uint4*)&lds[r * 64 + q * 4];
    }
}

// ---------------- CSR scan ----------------

// parallel scan, phase A. Fused: dinv; coalesced zeroing of this block's c rows
// + self-loop term c[i][batch[i]] = dinv_i^2 (ordered by the block barrier).
__global__ __launch_bounds__(1024) void scanA_kernel(const int* __restrict__ cnt,
                                                     int* __restrict__ rowptr,
                                                     int* __restrict__ tot,
                                                     float* __restrict__ dinv,
                                                     float* __restrict__ c,
                                                     const int* __restrict__ batch, int n) {
    __shared__ int swave[16];
    int t = threadIdx.x;
    int lane = t & 63, wave = t >> 6;
    int i = blockIdx.x * 1024 + t;
    // coalesced zero of c rows [blockIdx*1024, +1024) — replaces a 10.24MB memset
    {
        size_t f4base = (size_t)blockIdx.x * 1024 * 16;  // 16 float4 per 64-float row
        size_t f4lim = (size_t)n * 16;
        float4 z = make_float4(0.f, 0.f, 0.f, 0.f);
#pragma unroll
        for (int q = 0; q < 16; ++q) {
            size_t idx = f4base + (size_t)q * 1024 + t;
            if (idx < f4lim) ((float4*)c)[idx] = z;
        }
    }
    int orig = (i < n) ? cnt[i] : 0;
    int v = orig;
#pragma unroll
    for (int off = 1; off < 64; off <<= 1) {
        int u = __shfl_up(v, off, 64);
        if (lane >= off) v += u;
    }
    if (lane == 63) swave[wave] = v;
    __syncthreads();  // orders c-zeroing before the slot store below too
    if (wave == 0) {
        int wv = (lane < 16) ? swave[lane] : 0;
#pragma unroll
        for (int off = 1; off < 16; off <<= 1) {
            int u = __shfl_up(wv, off, 64);
            if (lane >= off) wv += u;
        }
        if (lane < 16) swave[lane] = wv;
    }
    if (i < n) {
        float dv = rsqrtf((float)(orig + 1));  // deg = in-deg + self loop
        dinv[i] = dv;
        c[(size_t)i * N_GRAPHS + batch[i]] = dv * dv;  // self-loop contribution
    }
    __syncthreads();
    int incl = v + ((wave > 0) ? swave[wave - 1] : 0);
    if (i < n) rowptr[i] = incl - orig;  // chunk-local exclusive
    if (t == 1023) tot[blockIdx.x] = incl;
}

// phase B: add chunk offsets (<=40 totals: serial per-block prefix is cheap)
__global__ __launch_bounds__(1024) void scanB_kernel(int* __restrict__ rowptr,
                                                     const int* __restrict__ tot,
                                                     int n, int nchunks) {
    __shared__ int soff;
    int b = blockIdx.x, t = threadIdx.x;
    if (t == 0) {
        int o = 0;
        for (int j = 0; j < b; ++j) o += tot[j];
        soff = o;
    }
    __syncthreads();
    int i = b * 1024 + t;
    if (i < n) rowptr[i] += soff;
    if (b == 0 && t == 0) {
        int o = 0;
        for (int j = 0; j < nchunks; ++j) o += tot[j];
        rowptr[n] = o;
    }
}

// fill: pure CSR col scatter (4B/edge). The c edge-atomics moved to agg
// (fire-and-forget there, hidden under gather latency) — R1's profile showed
// 41MB of memory-side atomic RMW flushes dominating this kernel.
__global__ void fill_kernel(const int* __restrict__ src, const int* __restrict__ dst,
                            const int* __restrict__ rowptr, const int* __restrict__ rank,
                            int* __restrict__ col, int E) {
    int e = blockIdx.x * blockDim.x + threadIdx.x;
    if (e < E) col[rowptr[dst[e]] + rank[e]] = src[e];
}

// ---------------- aggregation (gather over CSR) + bias + ReLU -> fp16 H1 --------
// fp16 rows: 32-lane group per node, uint2 (8B = 4 fp16) per lane = 256B row/load.
// Unroll x8 is the measured optimum (x16 regressed on VGPR/occupancy — R11).
// NEW: accumulates the c edge terms c[s][batch[node]] += w here. The atomic has
// no return use -> no critical-path stall; lane j of each 32-group issues edge
// j's atomic (w[j] is identical across lanes), pipelining 8 per chunk.

__global__ __launch_bounds__(128) void agg_kernel(const uint32* __restrict__ hb,
                                                  const int* __restrict__ rowptr,
                                                  const int* __restrict__ col,
                                                  const float* __restrict__ dinv,
                                                  const float* __restrict__ bias,
                                                  const int* __restrict__ batch,
                                                  float* __restrict__ c,
                                                  uint32* __restrict__ h1, int n) {
    int tid = threadIdx.x;
    int lane32 = tid & 31;   // features 4*lane32 .. 4*lane32+3
    int slot = tid >> 5;     // 0..3
    int node = blockIdx.x * 4 + slot;
    if (node >= n) return;
    const uint2* __restrict__ h2 = (const uint2*)hb;  // 32 uint2 per row

    float di = dinv[node];
    int bg = batch[node];
    float ws = di * di;
    uint2 su = h2[(size_t)node * 32 + lane32];
    float a0 = ws * hl(su.x), a1 = ws * hh(su.x);
    float a2 = ws * hl(su.y), a3 = ws * hh(su.y);

    int k = rowptr[node], end = rowptr[node + 1];
    for (; k + 8 <= end; k += 8) {
        uint2 v[8];
        float w[8];
#pragma unroll
        for (int j = 0; j < 8; ++j) {
            int s = col[k + j];
            w[j] = dinv[s] * di;
            v[j] = h2[(size_t)s * 32 + lane32];
            if (lane32 == j) atomicAdd(&c[(size_t)s * N_GRAPHS + bg], w[j]);
        }
#pragma unroll
        for (int j = 0; j < 8; ++j) {
            a0 = fmaf(w[j], hl(v[j].x), a0);
            a1 = fmaf(w[j], hh(v[j].x), a1);
            a2 = fmaf(w[j], hl(v[j].y), a2);
            a3 = fmaf(w[j], hh(v[j].y), a3);
        }
    }
    for (; k < end; ++k) {
        int s = col[k];
        float w = dinv[s] * di;
        uint2 v = h2[(size_t)s * 32 + lane32];
        if (lane32 == 0) atomicAdd(&c[(size_t)s * N_GRAPHS + bg], w);
        a0 = fmaf(w, hl(v.x), a0);
        a1 = fmaf(w, hh(v.x), a1);
        a2 = fmaf(w, hl(v.y), a2);
        a3 = fmaf(w, hh(v.y), a3);
    }

    float4 b4 = ((const float4*)bias)[lane32];
    a0 = fmaxf(a0 + b4.x, 0.f);
    a1 = fmaxf(a1 + b4.y, 0.f);
    a2 = fmaxf(a2 + b4.z, 0.f);
    a3 = fmaxf(a3 + b4.w, 0.f);
    uint2 o;
    o.x = h2pair(a0, a1);
    o.y = h2pair(a2, a3);
    ((uint2*)h1)[(size_t)node * 32 + lane32] = o;
}

// ---------------- pooled layer 2: out = rinv * (c^T H1) W2 + b2 ----------------

// Gp partials: Ppart[b][g][f] = sum_{j in block b's range} c[j][g] * H1[j][f]
// GP_NB=256: one block per CU — 128 left half the GPU idle (R11 regression).
#define GP_NB 256
#define GP_T 16

__global__ __launch_bounds__(256) void gp_kernel(const float* __restrict__ c,
                                                 const uint32* __restrict__ H1,
                                                 float* __restrict__ Ppart, int n) {
    __shared__ float sc[GP_T][N_GRAPHS];
    __shared__ uint32 sh[GP_T][64];  // fp16 pairs: 128 feats = 64 dwords
    int t = threadIdx.x;
    int b = blockIdx.x;
    int jpb = (n + GP_NB - 1) / GP_NB;
    int j0 = b * jpb;
    int j1 = min(j0 + jpb, n);
    int g0 = (t & 7) * 8;    // 8 graphs per thread
    int f0 = (t >> 3) * 4;   // 4 feats per thread (dwords f0/2, f0/2+1)
    float acc[8][4];
#pragma unroll
    for (int a = 0; a < 8; ++a)
#pragma unroll
        for (int q = 0; q < 4; ++q) acc[a][q] = 0.f;

    for (int jt = j0; jt < j1; jt += GP_T) {
        int cnt = min(GP_T, j1 - jt);
        // stage c tile: GP_T x 64 floats = 256 float4, 1/thread
        {
            int r = t >> 4, q = t & 15;
            float4 v = (r < cnt) ? *(const float4*)&c[(size_t)(jt + r) * N_GRAPHS + q * 4]
                                 : make_float4(0.f, 0.f, 0.f, 0.f);
            *(float4*)&sc[r][q * 4] = v;
        }
        // stage H1 fp16 tile: GP_T rows x 16 uint4 = 256, 1/thread
        {
            int r = t >> 4, q = t & 15;
            uint4 v = make_uint4(0, 0, 0, 0);
            if (r < cnt) v = *(const uint4*)&H1[(size_t)(jt + r) * 64 + q * 4];
            *(uint4*)&sh[r][q * 4] = v;
        }
        __syncthreads();
#pragma unroll
        for (int r = 0; r < GP_T; ++r) {  // zero-padded rows contribute 0
            float cw[8], hv[4];
            *(float4*)&cw[0] = *(float4*)&sc[r][g0];
            *(float4*)&cw[4] = *(float4*)&sc[r][g0 + 4];
            uint32 u0 = sh[r][f0 >> 1], u1 = sh[r][(f0 >> 1) + 1];
            hv[0] = hl(u0); hv[1] = hh(u0); hv[2] = hl(u1); hv[3] = hh(u1);
#pragma unroll
            for (int a = 0; a < 8; ++a)
#pragma unroll
                for (int q = 0; q < 4; ++q) acc[a][q] = fmaf(cw[a], hv[q], acc[a][q]);
        }
        __syncthreads();
    }
    float* P = &Ppart[(size_t)b * N_GRAPHS * D];
#pragma unroll
    for (int a = 0; a < 8; ++a)
        *(float4*)&P[(size_t)(g0 + a) * D + f0] =
            make_float4(acc[a][0], acc[a][1], acc[a][2], acc[a][3]);
}

// epilogue: out[g][f] = rinv_g * sum_k (sum_b Ppart[b][g][k]) * W2[k][f] + b2[f]
// 256 threads: both the 256-deep partial-sum and the 128-deep W2 dot are split
// 2-way across halves (LDS combine) — halves the serial depth of each loop.
__global__ __launch_bounds__(256) void out_kernel(const float* __restrict__ Ppart,
                                                  const float* __restrict__ W2,
                                                  const float* __restrict__ b2,
                                                  const int* __restrict__ batch, int n,
                                                  float* __restrict__ out) {
    __shared__ float gs[D];
    __shared__ float part[2][D];
    __shared__ float srinv;
    int g = blockIdx.x, t = threadIdx.x;
    int f = t & 127, half = t >> 7;
    if (t == 0) {
        int lo = 0, hi = n;
        while (lo < hi) { int mid = (lo + hi) >> 1; if (batch[mid] < g) lo = mid + 1; else hi = mid; }
        int lb = lo;
        int g1 = g + 1;
        lo = 0; hi = n;
        while (lo < hi) { int mid = (lo + hi) >> 1; if (batch[mid] < g1) lo = mid + 1; else hi = mid; }
        int cg = lo - lb;
        srinv = (cg > 0) ? 1.0f / (float)cg : 0.0f;
    }
    float s = 0.f;
    int b0 = half * (GP_NB / 2);
#pragma unroll 8
    for (int b = b0; b < b0 + GP_NB / 2; ++b)
        s += Ppart[((size_t)b * N_GRAPHS + g) * D + f];
    part[half][f] = s;
    __syncthreads();
    if (half == 0) gs[f] = part[0][f] + part[1][f];
    __syncthreads();
    float acc = 0.f;
    int k0 = half * (D / 2);
#pragma unroll 8
    for (int k = k0; k < k0 + D / 2; ++k) acc = fmaf(gs[k], W2[k * D + f], acc);
    part[half][f] = acc;
    __syncthreads();
    if (half == 0) {
        float a = part[0][f] + part[1][f];
        float r = srinv;
        out[g * D + f] = (r > 0.f) ? fmaf(a, r, b2[f]) : 0.f;  // empty graph -> 0 (matches ref)
    }
}

// ---------------- launcher ----------------

extern "C" void kernel_launch(void* const* d_in, const int* in_sizes, int n_in,
                              void* d_out, int out_size, void* d_ws, size_t ws_size,
                              hipStream_t stream) {
    const float* x  = (const float*)d_in[0];
    const int*   ei = (const int*)d_in[1];
    const int*   batch = (const int*)d_in[2];
    const float* W1 = (const float*)d_in[3];
    const float* b1 = (const float*)d_in[4];
    const float* W2 = (const float*)d_in[5];
    const float* b2 = (const float*)d_in[6];
    float* out = (float*)d_out;

    const int n = in_sizes[2];       // 40000 nodes
    const int E = in_sizes[1] / 2;   // 640000 edges
    const int* src = ei;             // edge_index[0] = message sources
    const int* dst = ei + E;         // edge_index[1] = aggregation targets

    // workspace carve-up (256B aligned)
    char* ws = (char*)d_ws;
    size_t off = 0;
    auto carve = [&](size_t bytes) {
        size_t o = off;
        off = (off + bytes + 255) & ~(size_t)255;
        return (void*)(ws + o);
    };
    int*    cnt    = (int*)carve((size_t)n * 4);
    int*    rowptr = (int*)carve((size_t)(n + 1) * 4);
    float*  dinv   = (float*)carve((size_t)n * 4);
    int*    col    = (int*)carve((size_t)E * 4);                 // CSR col (2.56MB)
    uint32* hb     = (uint32*)carve((size_t)n * D * 2);          // fp16 feature rows (10.24MB)
    uint32* h1     = (uint32*)carve((size_t)n * D * 2);          // fp16 H1 rows (10.24MB)
    float*  c      = (float*)carve((size_t)n * N_GRAPHS * 4);    // pooled coeffs (10.24MB)
    int*    tot    = (int*)carve(64 * 4);
    int*    rank   = (int*)carve((size_t)E * 4);                 // own carve: gemm role writes
                                                                 // hb WHILE count writes rank
    uint32* Wh     = (uint32*)carve((size_t)D * (D / 2) * 4);    // fp16 W1^T (32KB)
    // Ppart (8MB) aliases hb: written by gp strictly after agg's last read of hb
    float*  Ppart  = (float*)hb;
    (void)ws_size;

    const int nchunks = (n + 1023) >> 10;

    // prep replaces the cnt memset dispatch; also builds fp16 W1^T for the gemm
    prep_kernel<<<(n + D * (D / 2) + 255) / 256, 256, 0, stream>>>(cnt, W1, Wh, n);

    // fused dispatch: gemm blocks first, then count blocks (gemm hides under
    // the 640K-atomic count_rank stretch)
    const int gemmBlocks = (n + GBM - 1) / GBM;
    const int countBlocks = (E + 255) / 256;
    count_gemm_kernel<<<gemmBlocks + countBlocks, 256, 0, stream>>>(
        x, Wh, hb, n, gemmBlocks, dst, cnt, rank, E);

    // CSR scan + pure col scatter
    scanA_kernel<<<nchunks, 1024, 0, stream>>>(cnt, rowptr, tot, dinv, c, batch, n);
    scanB_kernel<<<nchunks, 1024, 0, stream>>>(rowptr, tot, n, nchunks);
    fill_kernel<<<(E + 255) / 256, 256, 0, stream>>>(src, dst, rowptr, rank, col, E);

    // layer 1 aggregation + b1 + ReLU -> h1 (fp16); c edge-atomics fused here
    agg_kernel<<<(n + 3) / 4, 128, 0, stream>>>(hb, rowptr, col, dinv, b1, batch, c, h1, n);

    // layer 2 + pool, algebraically fused: out = rinv * (c^T H1) W2 + b2
    gp_kernel<<<GP_NB, 256, 0, stream>>>(c, h1, Ppart, n);
    out_kernel<<<N_GRAPHS, 256, 0, stream>>>(Ppart, W2, b2, batch, n, out);
}

// Round 3
// 201.239 us; speedup vs baseline: 1.1377x; 1.1377x over previous
//
#include <hip/hip_runtime.h>

#define D 128
#define N_GRAPHS 64

typedef unsigned int uint32;
typedef __attribute__((ext_vector_type(8))) _Float16 f16x8;
typedef __attribute__((ext_vector_type(4))) float f32x4;

// fp16 helpers: dword holds 2 fp16 (low = elem 2i, high = elem 2i+1); RNE cvt
__device__ __forceinline__ float hl(uint32 u) {
    return (float)__builtin_bit_cast(_Float16, (unsigned short)(u & 0xFFFF));
}
__device__ __forceinline__ float hh(uint32 u) {
    return (float)__builtin_bit_cast(_Float16, (unsigned short)(u >> 16));
}
__device__ __forceinline__ uint32 h2pair(float a, float b) {
    unsigned short ua = __builtin_bit_cast(unsigned short, (_Float16)a);
    unsigned short ub = __builtin_bit_cast(unsigned short, (_Float16)b);
    return (uint32)ua | ((uint32)ub << 16);
}

// ---------------- prep: zero cnt + pre-convert W1 -> fp16 W^T ----------------
// Replaces the hipMemsetAsync dispatch. Wh[n][kd] holds fp16 pair
// (W1[2kd][n], W1[2kd+1][n]) — the MFMA B-fragment layout, unpadded.
__global__ __launch_bounds__(256) void prep_kernel(int* __restrict__ cnt,
                                                   const float* __restrict__ W1,
                                                   uint32* __restrict__ Wh, int n) {
    int i = blockIdx.x * 256 + threadIdx.x;
    if (i < n) {
        cnt[i] = 0;
    } else if (i < n + D * (D / 2)) {
        int j = i - n;
        int nn = j & 127, kd = j >> 7;  // consecutive threads -> consecutive nn (coalesced reads)
        float v0 = W1[(size_t)(2 * kd) * D + nn];
        float v1 = W1[(size_t)(2 * kd + 1) * D + nn];
        Wh[nn * 64 + kd] = h2pair(v0, v1);
    }
}

// ---------------- fused count_rank + MFMA GEMM (independent, one dispatch) ----
// The 640K-atomic count stretch (~40us) hides the 15-20us gemm. R2 lesson:
// the OTHER 640K c-atomics cost ~40us no matter which kernel hosts them
// (op-rate-limited, 64B RMW line each) — so they are now ELIMINATED entirely:
// layer-2 pooling is computed by a second gather (agg2pool) instead of a
// scattered c-matrix. CSR build keeps exactly ONE atomic pass (this one).
// NOTE: rank/cnt must not alias hb (written concurrently by gemm role).

#define GBM 64

__global__ __launch_bounds__(256) void count_gemm_kernel(
    const float* __restrict__ A, const uint32* __restrict__ Wh,
    uint32* __restrict__ hb, int M, int gemmBlocks,
    const int* __restrict__ dst, int* __restrict__ cnt,
    int* __restrict__ rank, int E) {
    __shared__ uint32 lds[64 * 68];  // As 17408B; reused as C staging in epilogue

    if (blockIdx.x >= gemmBlocks) {
        // ---- count role: in-degree + per-edge rank among its dst's edges ----
        int e = (blockIdx.x - gemmBlocks) * 256 + threadIdx.x;
        if (e < E) rank[e] = atomicAdd(&cnt[dst[e]], 1);
        return;
    }

    // ---- gemm role ----
    uint32* As = lds;  // [64 rows][68 dw]
    int tid = threadIdx.x;
    int row0 = blockIdx.x * GBM;

    // stage A tile: 64x128 fp32 -> fp16 (2048 float4, 8/thread, coalesced)
#pragma unroll
    for (int j = 0; j < 8; ++j) {
        int idx = tid + j * 256;
        int r = idx >> 5, c4 = idx & 31;
        float4 v = make_float4(0.f, 0.f, 0.f, 0.f);
        if (row0 + r < M) v = *(const float4*)&A[(size_t)(row0 + r) * D + c4 * 4];
        As[r * 68 + c4 * 2 + 0] = h2pair(v.x, v.y);
        As[r * 68 + c4 * 2 + 1] = h2pair(v.z, v.w);
    }
    __syncthreads();

    int wave = tid >> 6, lane = tid & 63;
    int quad = lane >> 4, l16 = lane & 15;
    int wr = (wave & 1) * 32;   // wave row base (2 m-tiles)
    int wc = (wave >> 1) * 64;  // wave col base (4 n-tiles)
    f32x4 acc[2][4];
#pragma unroll
    for (int mi = 0; mi < 2; ++mi)
#pragma unroll
        for (int ni = 0; ni < 4; ++ni) acc[mi][ni] = (f32x4){0.f, 0.f, 0.f, 0.f};

#pragma unroll
    for (int ks = 0; ks < 4; ++ks) {
        int kd = ks * 16 + quad * 4;  // dword offset of k0 + quad*8 fp16
        f16x8 a0 = *(f16x8*)&As[(wr + l16) * 68 + kd];
        f16x8 a1 = *(f16x8*)&As[(wr + 16 + l16) * 68 + kd];
        f16x8 b0 = *(const f16x8*)&Wh[(wc + l16) * 64 + kd];
        f16x8 b1 = *(const f16x8*)&Wh[(wc + 16 + l16) * 64 + kd];
        f16x8 b2 = *(const f16x8*)&Wh[(wc + 32 + l16) * 64 + kd];
        f16x8 b3 = *(const f16x8*)&Wh[(wc + 48 + l16) * 64 + kd];
        acc[0][0] = __builtin_amdgcn_mfma_f32_16x16x32_f16(a0, b0, acc[0][0], 0, 0, 0);
        acc[0][1] = __builtin_amdgcn_mfma_f32_16x16x32_f16(a0, b1, acc[0][1], 0, 0, 0);
        acc[0][2] = __builtin_amdgcn_mfma_f32_16x16x32_f16(a0, b2, acc[0][2], 0, 0, 0);
        acc[0][3] = __builtin_amdgcn_mfma_f32_16x16x32_f16(a0, b3, acc[0][3], 0, 0, 0);
        acc[1][0] = __builtin_amdgcn_mfma_f32_16x16x32_f16(a1, b0, acc[1][0], 0, 0, 0);
        acc[1][1] = __builtin_amdgcn_mfma_f32_16x16x32_f16(a1, b1, acc[1][1], 0, 0, 0);
        acc[1][2] = __builtin_amdgcn_mfma_f32_16x16x32_f16(a1, b2, acc[1][2], 0, 0, 0);
        acc[1][3] = __builtin_amdgcn_mfma_f32_16x16x32_f16(a1, b3, acc[1][3], 0, 0, 0);
    }
    __syncthreads();  // done reading As; reuse As region as C staging [64][128] fp16

    unsigned short* cs = (unsigned short*)lds;
#pragma unroll
    for (int mi = 0; mi < 2; ++mi)
#pragma unroll
        for (int ni = 0; ni < 4; ++ni)
#pragma unroll
            for (int r = 0; r < 4; ++r) {
                int row = wr + mi * 16 + quad * 4 + r;
                int col2 = wc + ni * 16 + l16;
                cs[row * 128 + col2] =
                    __builtin_bit_cast(unsigned short, (_Float16)acc[mi][ni][r]);
            }
    __syncthreads();
    // coalesced write-out: 64 rows x 16 uint4; C-staging row = 128 fp16 = 64 dwords
#pragma unroll
    for (int j = 0; j < 4; ++j) {
        int idx = tid + j * 256;
        int r = idx >> 4, q = idx & 15;
        if (row0 + r < M)
            *(uint4*)&hb[(size_t)(row0 + r) * 64 + q * 4] = *(uint4*)&lds[r * 64 + q * 4];
    }
}

// ---------------- CSR scan ----------------

// parallel scan, phase A. Fused: dinv. (c-matrix and its zeroing are gone.)
__global__ __launch_bounds__(1024) void scanA_kernel(const int* __restrict__ cnt,
                                                     int* __restrict__ rowptr,
                                                     int* __restrict__ tot,
                                                     float* __restrict__ dinv, int n) {
    __shared__ int swave[16];
    int t = threadIdx.x;
    int lane = t & 63, wave = t >> 6;
    int i = blockIdx.x * 1024 + t;
    int orig = (i < n) ? cnt[i] : 0;
    int v = orig;
#pragma unroll
    for (int off = 1; off < 64; off <<= 1) {
        int u = __shfl_up(v, off, 64);
        if (lane >= off) v += u;
    }
    if (lane == 63) swave[wave] = v;
    __syncthreads();
    if (wave == 0) {
        int wv = (lane < 16) ? swave[lane] : 0;
#pragma unroll
        for (int off = 1; off < 16; off <<= 1) {
            int u = __shfl_up(wv, off, 64);
            if (lane >= off) wv += u;
        }
        if (lane < 16) swave[lane] = wv;
    }
    if (i < n) dinv[i] = rsqrtf((float)(orig + 1));  // deg = in-deg + self loop
    __syncthreads();
    int incl = v + ((wave > 0) ? swave[wave - 1] : 0);
    if (i < n) rowptr[i] = incl - orig;  // chunk-local exclusive
    if (t == 1023) tot[blockIdx.x] = incl;
}

// phase B: add chunk offsets (<=40 totals: serial per-block prefix is cheap)
__global__ __launch_bounds__(1024) void scanB_kernel(int* __restrict__ rowptr,
                                                     const int* __restrict__ tot,
                                                     int n, int nchunks) {
    __shared__ int soff;
    int b = blockIdx.x, t = threadIdx.x;
    if (t == 0) {
        int o = 0;
        for (int j = 0; j < b; ++j) o += tot[j];
        soff = o;
    }
    __syncthreads();
    int i = b * 1024 + t;
    if (i < n) rowptr[i] += soff;
    if (b == 0 && t == 0) {
        int o = 0;
        for (int j = 0; j < nchunks; ++j) o += tot[j];
        rowptr[n] = o;
    }
}

// fill: pure CSR col scatter (4B/edge), ~5us.
__global__ void fill_kernel(const int* __restrict__ src, const int* __restrict__ dst,
                            const int* __restrict__ rowptr, const int* __restrict__ rank,
                            int* __restrict__ col, int E) {
    int e = blockIdx.x * blockDim.x + threadIdx.x;
    if (e < E) col[rowptr[dst[e]] + rank[e]] = src[e];
}

// ---------------- layer-1 aggregation (gather) + bias + ReLU -> fp16 H1 --------
// fp16 rows: 32-lane group per node, uint2 (8B = 4 fp16) per lane = 256B row/load.
// Unroll x8 is the measured optimum. No atomics (R2 lesson: they cost 40us here).

__global__ __launch_bounds__(128) void agg_kernel(const uint32* __restrict__ hb,
                                                  const int* __restrict__ rowptr,
                                                  const int* __restrict__ col,
                                                  const float* __restrict__ dinv,
                                                  const float* __restrict__ bias,
                                                  uint32* __restrict__ h1, int n) {
    int tid = threadIdx.x;
    int lane32 = tid & 31;   // features 4*lane32 .. 4*lane32+3
    int slot = tid >> 5;     // 0..3
    int node = blockIdx.x * 4 + slot;
    if (node >= n) return;
    const uint2* __restrict__ h2 = (const uint2*)hb;  // 32 uint2 per row

    float di = dinv[node];
    float ws = di * di;
    uint2 su = h2[(size_t)node * 32 + lane32];
    float a0 = ws * hl(su.x), a1 = ws * hh(su.x);
    float a2 = ws * hl(su.y), a3 = ws * hh(su.y);

    int k = rowptr[node], end = rowptr[node + 1];
    for (; k + 8 <= end; k += 8) {
        uint2 v[8];
        float w[8];
#pragma unroll
        for (int j = 0; j < 8; ++j) {
            int s = col[k + j];
            w[j] = dinv[s] * di;
            v[j] = h2[(size_t)s * 32 + lane32];
        }
#pragma unroll
        for (int j = 0; j < 8; ++j) {
            a0 = fmaf(w[j], hl(v[j].x), a0);
            a1 = fmaf(w[j], hh(v[j].x), a1);
            a2 = fmaf(w[j], hl(v[j].y), a2);
            a3 = fmaf(w[j], hh(v[j].y), a3);
        }
    }
    for (; k < end; ++k) {
        int s = col[k];
        float w = dinv[s] * di;
        uint2 v = h2[(size_t)s * 32 + lane32];
        a0 = fmaf(w, hl(v.x), a0);
        a1 = fmaf(w, hh(v.x), a1);
        a2 = fmaf(w, hl(v.y), a2);
        a3 = fmaf(w, hh(v.y), a3);
    }

    float4 b4 = ((const float4*)bias)[lane32];
    a0 = fmaxf(a0 + b4.x, 0.f);
    a1 = fmaxf(a1 + b4.y, 0.f);
    a2 = fmaxf(a2 + b4.z, 0.f);
    a3 = fmaxf(a3 + b4.w, 0.f);
    uint2 o;
    o.x = h2pair(a0, a1);
    o.y = h2pair(a2, a3);
    ((uint2*)h1)[(size_t)node * 32 + lane32] = o;
}

// ---------------- layer-2 aggregation + pooling, fused (NO atomics) ----------
// pooled_pre[g][f] = sum_{d in g} ( sum_{e:dst=d} w_e H1[src_e][f]
//                                   + dinv_d^2 H1[d][f] )
// Graph-aligned blocks: block = (g, k) of 64 x P2K; handles slice k of graph
// g's sorted node range. 8 node-slots of 32 lanes gather like agg; each slot
// accumulates into its PRIVATE LDS pool row (race-free), 8 rows tree-reduced
// at the end into Ppart[g*P2K+k][128]. W2/b2/rinv applied later in out.
#define P2K 32

__global__ __launch_bounds__(256) void agg2pool_kernel(const uint32* __restrict__ h1,
                                                       const int* __restrict__ rowptr,
                                                       const int* __restrict__ col,
                                                       const float* __restrict__ dinv,
                                                       const int* __restrict__ batch,
                                                       float* __restrict__ Ppart, int n) {
    __shared__ float pool[8][D];
    __shared__ int srange[2];
    int t = threadIdx.x;
    int g = blockIdx.x >> 5;       // / P2K
    int kslice = blockIdx.x & 31;  // % P2K
    int lane32 = t & 31, slot = t >> 5;

    if (t == 0) {  // graph g's node range via binary search on sorted batch
        int lo = 0, hi = n;
        while (lo < hi) { int mid = (lo + hi) >> 1; if (batch[mid] < g) lo = mid + 1; else hi = mid; }
        srange[0] = lo;
        int g1 = g + 1;
        lo = 0; hi = n;
        while (lo < hi) { int mid = (lo + hi) >> 1; if (batch[mid] < g1) lo = mid + 1; else hi = mid; }
        srange[1] = lo;
    }
    // zero this slot's private pool row (32 lanes x 4 floats)
    *(float4*)&pool[slot][lane32 * 4] = make_float4(0.f, 0.f, 0.f, 0.f);
    __syncthreads();

    int lb = srange[0], cntg = srange[1] - srange[0];
    int a = lb + (int)(((long long)cntg * kslice) >> 5);
    int b = lb + (int)(((long long)cntg * (kslice + 1)) >> 5);
    const uint2* __restrict__ h2 = (const uint2*)h1;

    for (int node = a + slot; node < b; node += 8) {
        float di = dinv[node];
        float ws = di * di;
        uint2 su = h2[(size_t)node * 32 + lane32];
        float a0 = ws * hl(su.x), a1 = ws * hh(su.x);
        float a2 = ws * hl(su.y), a3 = ws * hh(su.y);

        int k = rowptr[node], end = rowptr[node + 1];
        for (; k + 8 <= end; k += 8) {
            uint2 v[8];
            float w[8];
#pragma unroll
            for (int j = 0; j < 8; ++j) {
                int s = col[k + j];
                w[j] = dinv[s] * di;
                v[j] = h2[(size_t)s * 32 + lane32];
            }
#pragma unroll
            for (int j = 0; j < 8; ++j) {
                a0 = fmaf(w[j], hl(v[j].x), a0);
                a1 = fmaf(w[j], hh(v[j].x), a1);
                a2 = fmaf(w[j], hl(v[j].y), a2);
                a3 = fmaf(w[j], hh(v[j].y), a3);
            }
        }
        for (; k < end; ++k) {
            int s = col[k];
            float w = dinv[s] * di;
            uint2 v = h2[(size_t)s * 32 + lane32];
            a0 = fmaf(w, hl(v.x), a0);
            a1 = fmaf(w, hh(v.x), a1);
            a2 = fmaf(w, hl(v.y), a2);
            a3 = fmaf(w, hh(v.y), a3);
        }
        // slot-private accumulate (no race: each slot owns its pool row,
        // each lane owns 4 distinct feats)
        float4 p = *(float4*)&pool[slot][lane32 * 4];
        p.x += a0; p.y += a1; p.z += a2; p.w += a3;
        *(float4*)&pool[slot][lane32 * 4] = p;
    }
    __syncthreads();
    // tree-reduce 8 slot rows -> Ppart[blockIdx.x][f]
    if (t < D) {
        float s = 0.f;
#pragma unroll
        for (int sl = 0; sl < 8; ++sl) s += pool[sl][t];
        Ppart[(size_t)blockIdx.x * D + t] = s;
    }
}

// epilogue: out[g][f] = rinv_g * (sum_k Ppart[g*P2K+k]) @ W2 + b2
// 256 threads: the P2K partial-sum and the 128-deep W2 dot each split 2-way.
__global__ __launch_bounds__(256) void out_kernel(const float* __restrict__ Ppart,
                                                  const float* __restrict__ W2,
                                                  const float* __restrict__ b2,
                                                  const int* __restrict__ batch, int n,
                                                  float* __restrict__ out) {
    __shared__ float gs[D];
    __shared__ float part[2][D];
    __shared__ float srinv;
    int g = blockIdx.x, t = threadIdx.x;
    int f = t & 127, half = t >> 7;
    if (t == 0) {
        int lo = 0, hi = n;
        while (lo < hi) { int mid = (lo + hi) >> 1; if (batch[mid] < g) lo = mid + 1; else hi = mid; }
        int lb = lo;
        int g1 = g + 1;
        lo = 0; hi = n;
        while (lo < hi) { int mid = (lo + hi) >> 1; if (batch[mid] < g1) lo = mid + 1; else hi = mid; }
        int cg = lo - lb;
        srinv = (cg > 0) ? 1.0f / (float)cg : 0.0f;
    }
    float s = 0.f;
    int j0 = half * (P2K / 2);
#pragma unroll
    for (int j = j0; j < j0 + P2K / 2; ++j)
        s += Ppart[((size_t)g * P2K + j) * D + f];
    part[half][f] = s;
    __syncthreads();
    if (half == 0) gs[f] = part[0][f] + part[1][f];
    __syncthreads();
    float acc = 0.f;
    int k0 = half * (D / 2);
#pragma unroll 8
    for (int k = k0; k < k0 + D / 2; ++k) acc = fmaf(gs[k], W2[k * D + f], acc);
    part[half][f] = acc;
    __syncthreads();
    if (half == 0) {
        float a = part[0][f] + part[1][f];
        float r = srinv;
        out[g * D + f] = (r > 0.f) ? fmaf(a, r, b2[f]) : 0.f;  // empty graph -> 0 (matches ref)
    }
}

// ---------------- launcher ----------------

extern "C" void kernel_launch(void* const* d_in, const int* in_sizes, int n_in,
                              void* d_out, int out_size, void* d_ws, size_t ws_size,
                              hipStream_t stream) {
    const float* x  = (const float*)d_in[0];
    const int*   ei = (const int*)d_in[1];
    const int*   batch = (const int*)d_in[2];
    const float* W1 = (const float*)d_in[3];
    const float* b1 = (const float*)d_in[4];
    const float* W2 = (const float*)d_in[5];
    const float* b2 = (const float*)d_in[6];
    float* out = (float*)d_out;

    const int n = in_sizes[2];       // 40000 nodes
    const int E = in_sizes[1] / 2;   // 640000 edges
    const int* src = ei;             // edge_index[0] = message sources
    const int* dst = ei + E;         // edge_index[1] = aggregation targets

    // workspace carve-up (256B aligned)
    char* ws = (char*)d_ws;
    size_t off = 0;
    auto carve = [&](size_t bytes) {
        size_t o = off;
        off = (off + bytes + 255) & ~(size_t)255;
        return (void*)(ws + o);
    };
    int*    cnt    = (int*)carve((size_t)n * 4);
    int*    rowptr = (int*)carve((size_t)(n + 1) * 4);
    float*  dinv   = (float*)carve((size_t)n * 4);
    int*    col    = (int*)carve((size_t)E * 4);                 // CSR col (2.56MB)
    uint32* hb     = (uint32*)carve((size_t)n * D * 2);          // fp16 feature rows (10.24MB)
    uint32* h1     = (uint32*)carve((size_t)n * D * 2);          // fp16 H1 rows (10.24MB)
    int*    tot    = (int*)carve(64 * 4);
    int*    rank   = (int*)carve((size_t)E * 4);                 // own carve: gemm role writes
                                                                 // hb WHILE count writes rank
    uint32* Wh     = (uint32*)carve((size_t)D * (D / 2) * 4);    // fp16 W1^T (32KB)
    // Ppart (64*P2K*128*4 = 1MB) aliases hb: agg2pool writes it strictly after
    // agg's last read of hb; every Ppart row is fully written before out reads.
    float*  Ppart  = (float*)hb;
    (void)ws_size;

    const int nchunks = (n + 1023) >> 10;

    // prep replaces the cnt memset dispatch; also builds fp16 W1^T for the gemm
    prep_kernel<<<(n + D * (D / 2) + 255) / 256, 256, 0, stream>>>(cnt, W1, Wh, n);

    // fused dispatch: gemm blocks first, then count blocks (gemm hides under
    // the single remaining 640K-atomic stretch)
    const int gemmBlocks = (n + GBM - 1) / GBM;
    const int countBlocks = (E + 255) / 256;
    count_gemm_kernel<<<gemmBlocks + countBlocks, 256, 0, stream>>>(
        x, Wh, hb, n, gemmBlocks, dst, cnt, rank, E);

    // CSR scan + pure col scatter
    scanA_kernel<<<nchunks, 1024, 0, stream>>>(cnt, rowptr, tot, dinv, n);
    scanB_kernel<<<nchunks, 1024, 0, stream>>>(rowptr, tot, n, nchunks);
    fill_kernel<<<(E + 255) / 256, 256, 0, stream>>>(src, dst, rowptr, rank, col, E);

    // layer 1 aggregation + b1 + ReLU -> h1 (fp16)
    agg_kernel<<<(n + 3) / 4, 128, 0, stream>>>(hb, rowptr, col, dinv, b1, h1, n);

    // layer 2 aggregation + pooling fused (atomic-free), then epilogue @W2
    agg2pool_kernel<<<N_GRAPHS * P2K, 256, 0, stream>>>(h1, rowptr, col, dinv, batch,
                                                        Ppart, n);
    out_kernel<<<N_GRAPHS, 256, 0, stream>>>(Ppart, W2, b2, batch, n, out);
}

// Round 4
// 193.110 us; speedup vs baseline: 1.1856x; 1.0421x over previous
//
#include <hip/hip_runtime.h>

#define D 128
#define N_GRAPHS 64

typedef unsigned int uint32;
typedef __attribute__((ext_vector_type(8))) _Float16 f16x8;
typedef __attribute__((ext_vector_type(4))) float f32x4;

// fp16 helpers: dword holds 2 fp16 (low = elem 2i, high = elem 2i+1); RNE cvt
__device__ __forceinline__ float hl(uint32 u) {
    return (float)__builtin_bit_cast(_Float16, (unsigned short)(u & 0xFFFF));
}
__device__ __forceinline__ float hh(uint32 u) {
    return (float)__builtin_bit_cast(_Float16, (unsigned short)(u >> 16));
}
__device__ __forceinline__ uint32 h2pair(float a, float b) {
    unsigned short ua = __builtin_bit_cast(unsigned short, (_Float16)a);
    unsigned short ub = __builtin_bit_cast(unsigned short, (_Float16)b);
    return (uint32)ua | ((uint32)ub << 16);
}

// ---------------- prep: zero cnt + pre-convert W1 -> fp16 W^T ----------------
// Replaces the hipMemsetAsync dispatch. Wh[n][kd] holds fp16 pair
// (W1[2kd][n], W1[2kd+1][n]) — the MFMA B-fragment layout, unpadded.
__global__ __launch_bounds__(256) void prep_kernel(int* __restrict__ cnt,
                                                   const float* __restrict__ W1,
                                                   uint32* __restrict__ Wh, int n) {
    int i = blockIdx.x * 256 + threadIdx.x;
    if (i < n) {
        cnt[i] = 0;
    } else if (i < n + D * (D / 2)) {
        int j = i - n;
        int nn = j & 127, kd = j >> 7;  // consecutive threads -> consecutive nn (coalesced reads)
        float v0 = W1[(size_t)(2 * kd) * D + nn];
        float v1 = W1[(size_t)(2 * kd + 1) * D + nn];
        Wh[nn * 64 + kd] = h2pair(v0, v1);
    }
}

// ---------------- fused count_rank + MFMA GEMM (independent, one dispatch) ----
// The 640K-atomic count stretch (~40us) hides the 15-20us gemm. The c-atomics
// are eliminated entirely (R2: 640K device atomics cost ~40us wherever hosted);
// CSR build keeps exactly ONE atomic pass (this one).
// NOTE: rank/cnt must not alias hb (written concurrently by gemm role).

#define GBM 64

__global__ __launch_bounds__(256) void count_gemm_kernel(
    const float* __restrict__ A, const uint32* __restrict__ Wh,
    uint32* __restrict__ hb, int M, int gemmBlocks,
    const int* __restrict__ dst, int* __restrict__ cnt,
    int* __restrict__ rank, int E) {
    __shared__ uint32 lds[64 * 68];  // As 17408B; reused as C staging in epilogue

    if (blockIdx.x >= gemmBlocks) {
        // ---- count role: in-degree + per-edge rank among its dst's edges ----
        int e = (blockIdx.x - gemmBlocks) * 256 + threadIdx.x;
        if (e < E) rank[e] = atomicAdd(&cnt[dst[e]], 1);
        return;
    }

    // ---- gemm role ----
    uint32* As = lds;  // [64 rows][68 dw]
    int tid = threadIdx.x;
    int row0 = blockIdx.x * GBM;

    // stage A tile: 64x128 fp32 -> fp16 (2048 float4, 8/thread, coalesced)
#pragma unroll
    for (int j = 0; j < 8; ++j) {
        int idx = tid + j * 256;
        int r = idx >> 5, c4 = idx & 31;
        float4 v = make_float4(0.f, 0.f, 0.f, 0.f);
        if (row0 + r < M) v = *(const float4*)&A[(size_t)(row0 + r) * D + c4 * 4];
        As[r * 68 + c4 * 2 + 0] = h2pair(v.x, v.y);
        As[r * 68 + c4 * 2 + 1] = h2pair(v.z, v.w);
    }
    __syncthreads();

    int wave = tid >> 6, lane = tid & 63;
    int quad = lane >> 4, l16 = lane & 15;
    int wr = (wave & 1) * 32;   // wave row base (2 m-tiles)
    int wc = (wave >> 1) * 64;  // wave col base (4 n-tiles)
    f32x4 acc[2][4];
#pragma unroll
    for (int mi = 0; mi < 2; ++mi)
#pragma unroll
        for (int ni = 0; ni < 4; ++ni) acc[mi][ni] = (f32x4){0.f, 0.f, 0.f, 0.f};

#pragma unroll
    for (int ks = 0; ks < 4; ++ks) {
        int kd = ks * 16 + quad * 4;  // dword offset of k0 + quad*8 fp16
        f16x8 a0 = *(f16x8*)&As[(wr + l16) * 68 + kd];
        f16x8 a1 = *(f16x8*)&As[(wr + 16 + l16) * 68 + kd];
        f16x8 b0 = *(const f16x8*)&Wh[(wc + l16) * 64 + kd];
        f16x8 b1 = *(const f16x8*)&Wh[(wc + 16 + l16) * 64 + kd];
        f16x8 b2 = *(const f16x8*)&Wh[(wc + 32 + l16) * 64 + kd];
        f16x8 b3 = *(const f16x8*)&Wh[(wc + 48 + l16) * 64 + kd];
        acc[0][0] = __builtin_amdgcn_mfma_f32_16x16x32_f16(a0, b0, acc[0][0], 0, 0, 0);
        acc[0][1] = __builtin_amdgcn_mfma_f32_16x16x32_f16(a0, b1, acc[0][1], 0, 0, 0);
        acc[0][2] = __builtin_amdgcn_mfma_f32_16x16x32_f16(a0, b2, acc[0][2], 0, 0, 0);
        acc[0][3] = __builtin_amdgcn_mfma_f32_16x16x32_f16(a0, b3, acc[0][3], 0, 0, 0);
        acc[1][0] = __builtin_amdgcn_mfma_f32_16x16x32_f16(a1, b0, acc[1][0], 0, 0, 0);
        acc[1][1] = __builtin_amdgcn_mfma_f32_16x16x32_f16(a1, b1, acc[1][1], 0, 0, 0);
        acc[1][2] = __builtin_amdgcn_mfma_f32_16x16x32_f16(a1, b2, acc[1][2], 0, 0, 0);
        acc[1][3] = __builtin_amdgcn_mfma_f32_16x16x32_f16(a1, b3, acc[1][3], 0, 0, 0);
    }
    __syncthreads();  // done reading As; reuse As region as C staging [64][128] fp16

    unsigned short* cs = (unsigned short*)lds;
#pragma unroll
    for (int mi = 0; mi < 2; ++mi)
#pragma unroll
        for (int ni = 0; ni < 4; ++ni)
#pragma unroll
            for (int r = 0; r < 4; ++r) {
                int row = wr + mi * 16 + quad * 4 + r;
                int col2 = wc + ni * 16 + l16;
                cs[row * 128 + col2] =
                    __builtin_bit_cast(unsigned short, (_Float16)acc[mi][ni][r]);
            }
    __syncthreads();
    // coalesced write-out: 64 rows x 16 uint4; C-staging row = 128 fp16 = 64 dwords
#pragma unroll
    for (int j = 0; j < 4; ++j) {
        int idx = tid + j * 256;
        int r = idx >> 4, q = idx & 15;
        if (row0 + r < M)
            *(uint4*)&hb[(size_t)(row0 + r) * 64 + q * 4] = *(uint4*)&lds[r * 64 + q * 4];
    }
}

// ---------------- CSR scan ----------------

// parallel scan, phase A. Fused: dinv.
__global__ __launch_bounds__(1024) void scanA_kernel(const int* __restrict__ cnt,
                                                     int* __restrict__ rowptr,
                                                     int* __restrict__ tot,
                                                     float* __restrict__ dinv, int n) {
    __shared__ int swave[16];
    int t = threadIdx.x;
    int lane = t & 63, wave = t >> 6;
    int i = blockIdx.x * 1024 + t;
    int orig = (i < n) ? cnt[i] : 0;
    int v = orig;
#pragma unroll
    for (int off = 1; off < 64; off <<= 1) {
        int u = __shfl_up(v, off, 64);
        if (lane >= off) v += u;
    }
    if (lane == 63) swave[wave] = v;
    __syncthreads();
    if (wave == 0) {
        int wv = (lane < 16) ? swave[lane] : 0;
#pragma unroll
        for (int off = 1; off < 16; off <<= 1) {
            int u = __shfl_up(wv, off, 64);
            if (lane >= off) wv += u;
        }
        if (lane < 16) swave[lane] = wv;
    }
    if (i < n) dinv[i] = rsqrtf((float)(orig + 1));  // deg = in-deg + self loop
    __syncthreads();
    int incl = v + ((wave > 0) ? swave[wave - 1] : 0);
    if (i < n) rowptr[i] = incl - orig;  // chunk-local exclusive
    if (t == 1023) tot[blockIdx.x] = incl;
}

// phase B: add chunk offsets (<=40 totals: serial per-block prefix is cheap)
__global__ __launch_bounds__(1024) void scanB_kernel(int* __restrict__ rowptr,
                                                     const int* __restrict__ tot,
                                                     int n, int nchunks) {
    __shared__ int soff;
    int b = blockIdx.x, t = threadIdx.x;
    if (t == 0) {
        int o = 0;
        for (int j = 0; j < b; ++j) o += tot[j];
        soff = o;
    }
    __syncthreads();
    int i = b * 1024 + t;
    if (i < n) rowptr[i] += soff;
    if (b == 0 && t == 0) {
        int o = 0;
        for (int j = 0; j < nchunks; ++j) o += tot[j];
        rowptr[n] = o;
    }
}

// fill: pure CSR col scatter (4B/edge), ~5us.
__global__ void fill_kernel(const int* __restrict__ src, const int* __restrict__ dst,
                            const int* __restrict__ rowptr, const int* __restrict__ rank,
                            int* __restrict__ col, int E) {
    int e = blockIdx.x * blockDim.x + threadIdx.x;
    if (e < E) col[rowptr[dst[e]] + rank[e]] = src[e];
}

// ---------------- layer-1 aggregation (gather) + bias + ReLU -> fp16 H1 --------
// fp16 rows: 32-lane group per node, uint2 (8B = 4 fp16) per lane = 256B row/load.
// 10000 small blocks: the deep block queue dynamically backfills wave slots —
// this structure measures ~1.8x faster than graph-aligned fixed-residency
// blocks on the identical gather (R3 lesson).

__global__ __launch_bounds__(128) void agg_kernel(const uint32* __restrict__ hb,
                                                  const int* __restrict__ rowptr,
                                                  const int* __restrict__ col,
                                                  const float* __restrict__ dinv,
                                                  const float* __restrict__ bias,
                                                  uint32* __restrict__ h1, int n) {
    int tid = threadIdx.x;
    int lane32 = tid & 31;   // features 4*lane32 .. 4*lane32+3
    int slot = tid >> 5;     // 0..3
    int node = blockIdx.x * 4 + slot;
    if (node >= n) return;
    const uint2* __restrict__ h2 = (const uint2*)hb;  // 32 uint2 per row

    float di = dinv[node];
    float ws = di * di;
    uint2 su = h2[(size_t)node * 32 + lane32];
    float a0 = ws * hl(su.x), a1 = ws * hh(su.x);
    float a2 = ws * hl(su.y), a3 = ws * hh(su.y);

    int k = rowptr[node], end = rowptr[node + 1];
    for (; k + 8 <= end; k += 8) {
        uint2 v[8];
        float w[8];
#pragma unroll
        for (int j = 0; j < 8; ++j) {
            int s = col[k + j];
            w[j] = dinv[s] * di;
            v[j] = h2[(size_t)s * 32 + lane32];
        }
#pragma unroll
        for (int j = 0; j < 8; ++j) {
            a0 = fmaf(w[j], hl(v[j].x), a0);
            a1 = fmaf(w[j], hh(v[j].x), a1);
            a2 = fmaf(w[j], hl(v[j].y), a2);
            a3 = fmaf(w[j], hh(v[j].y), a3);
        }
    }
    for (; k < end; ++k) {
        int s = col[k];
        float w = dinv[s] * di;
        uint2 v = h2[(size_t)s * 32 + lane32];
        a0 = fmaf(w, hl(v.x), a0);
        a1 = fmaf(w, hh(v.x), a1);
        a2 = fmaf(w, hl(v.y), a2);
        a3 = fmaf(w, hh(v.y), a3);
    }

    float4 b4 = ((const float4*)bias)[lane32];
    a0 = fmaxf(a0 + b4.x, 0.f);
    a1 = fmaxf(a1 + b4.y, 0.f);
    a2 = fmaxf(a2 + b4.z, 0.f);
    a3 = fmaxf(a3 + b4.w, 0.f);
    uint2 o;
    o.x = h2pair(a0, a1);
    o.y = h2pair(a2, a3);
    ((uint2*)h1)[(size_t)node * 32 + lane32] = o;
}

// ---------------- layer-2 aggregation: materialize P2[node][128] fp32 ---------
// Exact clone of agg's structure (minus bias/relu/fp16 pack): R3 showed the
// graph-sliced pooled variant loses 1.8x to this shape on the same gather
// (fixed 8-block/CU residency + tiny slot work items -> 44% occupancy).
// Pooling is a separate streaming pass (pool_kernel).

__global__ __launch_bounds__(128) void agg2_kernel(const uint32* __restrict__ h1,
                                                   const int* __restrict__ rowptr,
                                                   const int* __restrict__ col,
                                                   const float* __restrict__ dinv,
                                                   float* __restrict__ P2, int n) {
    int tid = threadIdx.x;
    int lane32 = tid & 31;
    int slot = tid >> 5;
    int node = blockIdx.x * 4 + slot;
    if (node >= n) return;
    const uint2* __restrict__ h2 = (const uint2*)h1;

    float di = dinv[node];
    float ws = di * di;
    uint2 su = h2[(size_t)node * 32 + lane32];
    float a0 = ws * hl(su.x), a1 = ws * hh(su.x);
    float a2 = ws * hl(su.y), a3 = ws * hh(su.y);

    int k = rowptr[node], end = rowptr[node + 1];
    for (; k + 8 <= end; k += 8) {
        uint2 v[8];
        float w[8];
#pragma unroll
        for (int j = 0; j < 8; ++j) {
            int s = col[k + j];
            w[j] = dinv[s] * di;
            v[j] = h2[(size_t)s * 32 + lane32];
        }
#pragma unroll
        for (int j = 0; j < 8; ++j) {
            a0 = fmaf(w[j], hl(v[j].x), a0);
            a1 = fmaf(w[j], hh(v[j].x), a1);
            a2 = fmaf(w[j], hl(v[j].y), a2);
            a3 = fmaf(w[j], hh(v[j].y), a3);
        }
    }
    for (; k < end; ++k) {
        int s = col[k];
        float w = dinv[s] * di;
        uint2 v = h2[(size_t)s * 32 + lane32];
        a0 = fmaf(w, hl(v.x), a0);
        a1 = fmaf(w, hh(v.x), a1);
        a2 = fmaf(w, hl(v.y), a2);
        a3 = fmaf(w, hh(v.y), a3);
    }

    *(float4*)&P2[(size_t)node * D + lane32 * 4] = make_float4(a0, a1, a2, a3);
}

// ---------------- pooling: segmented streaming sum of P2 by graph -------------
// Block (g, k of PSL): sums slice k of graph g's contiguous node range.
// Fully coalesced (thread f reads P2[node][f], consecutive f = consecutive
// addresses); ~20MB total at streaming BW. No gather, no atomics.
#define PSL 16

__global__ __launch_bounds__(128) void pool_kernel(const float* __restrict__ P2,
                                                   const int* __restrict__ batch,
                                                   float* __restrict__ Ppart, int n) {
    __shared__ int srange[2];
    int t = threadIdx.x;
    int g = blockIdx.x >> 4;       // / PSL
    int kslice = blockIdx.x & 15;  // % PSL
    if (t == 0) {
        int lo = 0, hi = n;
        while (lo < hi) { int mid = (lo + hi) >> 1; if (batch[mid] < g) lo = mid + 1; else hi = mid; }
        srange[0] = lo;
        int g1 = g + 1;
        lo = 0; hi = n;
        while (lo < hi) { int mid = (lo + hi) >> 1; if (batch[mid] < g1) lo = mid + 1; else hi = mid; }
        srange[1] = lo;
    }
    __syncthreads();
    int lb = srange[0], cntg = srange[1] - srange[0];
    int a = lb + (int)(((long long)cntg * kslice) >> 4);
    int b = lb + (int)(((long long)cntg * (kslice + 1)) >> 4);

    float s = 0.f;
    int node = a;
    for (; node + 4 <= b; node += 4) {
        float v0 = P2[(size_t)(node + 0) * D + t];
        float v1 = P2[(size_t)(node + 1) * D + t];
        float v2 = P2[(size_t)(node + 2) * D + t];
        float v3 = P2[(size_t)(node + 3) * D + t];
        s += (v0 + v1) + (v2 + v3);
    }
    for (; node < b; ++node) s += P2[(size_t)node * D + t];
    Ppart[(size_t)blockIdx.x * D + t] = s;
}

// epilogue: out[g][f] = rinv_g * (sum_k Ppart[g*PSL+k]) @ W2 + b2
// 256 threads: the PSL partial-sum and the 128-deep W2 dot each split 2-way.
__global__ __launch_bounds__(256) void out_kernel(const float* __restrict__ Ppart,
                                                  const float* __restrict__ W2,
                                                  const float* __restrict__ b2,
                                                  const int* __restrict__ batch, int n,
                                                  float* __restrict__ out) {
    __shared__ float gs[D];
    __shared__ float part[2][D];
    __shared__ float srinv;
    int g = blockIdx.x, t = threadIdx.x;
    int f = t & 127, half = t >> 7;
    if (t == 0) {
        int lo = 0, hi = n;
        while (lo < hi) { int mid = (lo + hi) >> 1; if (batch[mid] < g) lo = mid + 1; else hi = mid; }
        int lb = lo;
        int g1 = g + 1;
        lo = 0; hi = n;
        while (lo < hi) { int mid = (lo + hi) >> 1; if (batch[mid] < g1) lo = mid + 1; else hi = mid; }
        int cg = lo - lb;
        srinv = (cg > 0) ? 1.0f / (float)cg : 0.0f;
    }
    float s = 0.f;
    int j0 = half * (PSL / 2);
#pragma unroll
    for (int j = j0; j < j0 + PSL / 2; ++j)
        s += Ppart[((size_t)g * PSL + j) * D + f];
    part[half][f] = s;
    __syncthreads();
    if (half == 0) gs[f] = part[0][f] + part[1][f];
    __syncthreads();
    float acc = 0.f;
    int k0 = half * (D / 2);
#pragma unroll 8
    for (int k = k0; k < k0 + D / 2; ++k) acc = fmaf(gs[k], W2[k * D + f], acc);
    part[half][f] = acc;
    __syncthreads();
    if (half == 0) {
        float a = part[0][f] + part[1][f];
        float r = srinv;
        out[g * D + f] = (r > 0.f) ? fmaf(a, r, b2[f]) : 0.f;  // empty graph -> 0 (matches ref)
    }
}

// ---------------- launcher ----------------

extern "C" void kernel_launch(void* const* d_in, const int* in_sizes, int n_in,
                              void* d_out, int out_size, void* d_ws, size_t ws_size,
                              hipStream_t stream) {
    const float* x  = (const float*)d_in[0];
    const int*   ei = (const int*)d_in[1];
    const int*   batch = (const int*)d_in[2];
    const float* W1 = (const float*)d_in[3];
    const float* b1 = (const float*)d_in[4];
    const float* W2 = (const float*)d_in[5];
    const float* b2 = (const float*)d_in[6];
    float* out = (float*)d_out;

    const int n = in_sizes[2];       // 40000 nodes
    const int E = in_sizes[1] / 2;   // 640000 edges
    const int* src = ei;             // edge_index[0] = message sources
    const int* dst = ei + E;         // edge_index[1] = aggregation targets

    // workspace carve-up (256B aligned); ws_size ~256MB (poison-fill evidence)
    char* ws = (char*)d_ws;
    size_t off = 0;
    auto carve = [&](size_t bytes) {
        size_t o = off;
        off = (off + bytes + 255) & ~(size_t)255;
        return (void*)(ws + o);
    };
    int*    cnt    = (int*)carve((size_t)n * 4);
    int*    rowptr = (int*)carve((size_t)(n + 1) * 4);
    float*  dinv   = (float*)carve((size_t)n * 4);
    int*    col    = (int*)carve((size_t)E * 4);                 // CSR col (2.56MB)
    uint32* hb     = (uint32*)carve((size_t)n * D * 2);          // fp16 feature rows (10.24MB)
    uint32* h1     = (uint32*)carve((size_t)n * D * 2);          // fp16 H1 rows (10.24MB)
    int*    tot    = (int*)carve(64 * 4);
    int*    rank   = (int*)carve((size_t)E * 4);                 // own carve: gemm role writes
                                                                 // hb WHILE count writes rank
    uint32* Wh     = (uint32*)carve((size_t)D * (D / 2) * 4);    // fp16 W1^T (32KB)
    float*  P2     = (float*)carve((size_t)n * D * 4);           // layer-2 rows fp32 (20.48MB)
    // Ppart (64*PSL*128*4 = 512KB) aliases hb: pool writes it strictly after
    // agg's last read of hb (agg2 reads h1, not hb).
    float*  Ppart  = (float*)hb;
    (void)ws_size;

    const int nchunks = (n + 1023) >> 10;

    // prep replaces the cnt memset dispatch; also builds fp16 W1^T for the gemm
    prep_kernel<<<(n + D * (D / 2) + 255) / 256, 256, 0, stream>>>(cnt, W1, Wh, n);

    // fused dispatch: gemm blocks first, then count blocks (gemm hides under
    // the single remaining 640K-atomic stretch)
    const int gemmBlocks = (n + GBM - 1) / GBM;
    const int countBlocks = (E + 255) / 256;
    count_gemm_kernel<<<gemmBlocks + countBlocks, 256, 0, stream>>>(
        x, Wh, hb, n, gemmBlocks, dst, cnt, rank, E);

    // CSR scan + pure col scatter
    scanA_kernel<<<nchunks, 1024, 0, stream>>>(cnt, rowptr, tot, dinv, n);
    scanB_kernel<<<nchunks, 1024, 0, stream>>>(rowptr, tot, n, nchunks);
    fill_kernel<<<(E + 255) / 256, 256, 0, stream>>>(src, dst, rowptr, rank, col, E);

    // layer 1 aggregation + b1 + ReLU -> h1 (fp16)
    agg_kernel<<<(n + 3) / 4, 128, 0, stream>>>(hb, rowptr, col, dinv, b1, h1, n);

    // layer 2 aggregation (agg-style, materialized) + streaming pool + epilogue
    agg2_kernel<<<(n + 3) / 4, 128, 0, stream>>>(h1, rowptr, col, dinv, P2, n);
    pool_kernel<<<N_GRAPHS * PSL, 128, 0, stream>>>(P2, batch, Ppart, n);
    out_kernel<<<N_GRAPHS, 256, 0, stream>>>(Ppart, W2, b2, batch, n, out);
}